// Round 6
// baseline (1495.080 us; speedup 1.0000x reference)
//
#include <hip/hip_runtime.h>
#include <stdint.h>

// ---------- types ----------
typedef __attribute__((ext_vector_type(8))) short          short8;   // 8 x bf16
typedef __attribute__((ext_vector_type(8))) unsigned short u16x8;
typedef __attribute__((ext_vector_type(4))) float          f32x4;

#define K_DIM 4096
#define N_DIM 11008
#define M_DIM 8192
#define BM 256
#define BN 256
#define BK 64
#define NT (K_DIM / BK)     // 64 K-tiles
#define MT2 (M_DIM / BM)    // 32
#define NT2 (N_DIM / BN)    // 43

// RNE float -> bf16 bits
__device__ __forceinline__ unsigned short f2bf(float f) {
    union { float f; uint32_t u; } v; v.f = f;
    uint32_t u = v.u;
    return (unsigned short)((u + 0x7FFFu + ((u >> 16) & 1u)) >> 16);
}

// ---------- conversion kernels (8 elems/thread) ----------
__global__ void cvt_x_kernel(const float* __restrict__ x,
                             u16x8* __restrict__ xb, int n8) {
    int i = blockIdx.x * blockDim.x + threadIdx.x;
    if (i >= n8) return;
    const float4* p = (const float4*)x + 2 * (size_t)i;
    float4 a = p[0], b = p[1];
    u16x8 o;
    o[0] = f2bf(a.x); o[1] = f2bf(a.y); o[2] = f2bf(a.z); o[3] = f2bf(a.w);
    o[4] = f2bf(b.x); o[5] = f2bf(b.y); o[6] = f2bf(b.z); o[7] = f2bf(b.w);
    xb[i] = o;
}

__global__ void cvt_w_kernel(const int* __restrict__ w,
                             u16x8* __restrict__ wb, int n8) {
    int i = blockIdx.x * blockDim.x + threadIdx.x;
    if (i >= n8) return;
    const int4* p = (const int4*)w + 2 * (size_t)i;
    int4 a = p[0], b = p[1];
    u16x8 o;
    o[0] = f2bf((float)a.x); o[1] = f2bf((float)a.y);
    o[2] = f2bf((float)a.z); o[3] = f2bf((float)a.w);
    o[4] = f2bf((float)b.x); o[5] = f2bf((float)b.y);
    o[6] = f2bf((float)b.z); o[7] = f2bf((float)b.w);
    wb[i] = o;
}

// ---------- 256x256 GEMM, 4 barriers/tile, 2-phase read-ahead ----------
#define GLDS16(gsrc, ldst)                                                       \
    __builtin_amdgcn_global_load_lds(                                            \
        (const __attribute__((address_space(1))) void*)(gsrc),                   \
        (__attribute__((address_space(3))) void*)(ldst), 16, 0, 0)

#define BARSCHED() do { __builtin_amdgcn_s_barrier();                            \
                        __builtin_amdgcn_sched_barrier(0); } while (0)
#define VMCNT(n)  asm volatile("s_waitcnt vmcnt(" #n ")" ::: "memory")

__global__ __launch_bounds__(512, 2) void gemm2_kernel(
    const unsigned short* __restrict__ xb,   // [8192][4096] bf16
    const unsigned short* __restrict__ wb,   // [11008][4096] bf16
    const float* __restrict__ scale,
    const float* __restrict__ bias,
    float* __restrict__ out)
{
    __shared__ unsigned char sm[131072];
    char* smc = (char*)sm;

    const int T  = threadIdx.x;
    const int l  = T & 63;
    const int wv = T >> 6;
    const int wm = wv >> 2;      // 0..1
    const int wn = wv & 3;       // 0..3

    // XCD-aware, bn-major grid map (B panel shared across XCDs via L3)
    const int orig = blockIdx.x;
    const int xcd  = orig & 7;
    const int p    = orig >> 3;          // 0..171
    const int bm   = xcd * 4 + (p & 3);  // 0..31
    const int bn   = p >> 2;             // 0..42
    const size_t rowM0 = (size_t)bm * BM;
    const size_t rowN0 = (size_t)bn * BN;

    // ---- staging precompute (pre-swizzled global source, linear LDS dest) ----
    const int rowT = T >> 3;                                        // 0..63
    const int colT = ((((T & 7) * 16) ^ ((rowT & 7) << 4)) >> 1);   // elems
    const unsigned short* pAg = xb + (rowM0 + rowT) * (size_t)K_DIM + colT;
    const unsigned short* pBg = wb + (rowN0 + ((rowT >> 5) << 6) + (rowT & 31)) * (size_t)K_DIM + colT;

    auto stageA = [&](char* base, int Q, int kt) {
        #pragma unroll
        for (int c = 0; c < 2; ++c) {
            const unsigned short* src = pAg + (size_t)(c * 128 + Q * 64) * K_DIM + (size_t)kt * BK;
            char* dst = base + Q * 16384 + c * 8192 + T * 16;
            GLDS16(src, dst);
        }
    };
    auto stageB = [&](char* base, int Q, int kt) {
        #pragma unroll
        for (int c = 0; c < 2; ++c) {
            const unsigned short* src = pBg + (size_t)(c * 128 + Q * 32) * K_DIM + (size_t)kt * BK;
            char* dst = base + 32768 + Q * 16384 + c * 8192 + T * 16;
            GLDS16(src, dst);
        }
    };

    // ---- ds_read precompute ----
    const int sw     = (l & 7) << 4;
    const int inrow0 = (l >> 4) * 16;
    const int lowk0  = inrow0 ^ sw;
    const int lowk1  = (64 + inrow0) ^ sw;
    const int arow   = wm * 64 + (l & 15);
    const int brow   = wn * 32 + (l & 15);

    f32x4 acc[8][4];
    #pragma unroll
    for (int i = 0; i < 8; ++i)
        #pragma unroll
        for (int j = 0; j < 4; ++j)
            acc[i][j] = (f32x4){0.f, 0.f, 0.f, 0.f};

    // split operand register sets (2-phase read-ahead)
    short8 A0h[4][2];   // A quadrant q0 of current tile (or next, after p2 refill)
    short8 A1h[4][2];   // A quadrant q1
    short8 B0h[2][2];   // B half 0
    short8 B1h[2][2];   // B half 1

    char* const b0 = smc;
    char* const b1 = smc + 65536;

#define READ_A8(dst, base)                                                       \
    _Pragma("unroll")                                                            \
    for (int im = 0; im < 4; ++im) {                                             \
        dst[im][0] = *(const short8*)((base) + (arow + im * 16) * 128 + lowk0);  \
        dst[im][1] = *(const short8*)((base) + (arow + im * 16) * 128 + lowk1);  \
    }
#define READ_B4(dst, base)                                                       \
    _Pragma("unroll")                                                            \
    for (int f = 0; f < 2; ++f) {                                                \
        dst[f][0] = *(const short8*)((base) + (brow + f * 16) * 128 + lowk0);    \
        dst[f][1] = *(const short8*)((base) + (brow + f * 16) * 128 + lowk1);    \
    }
#define MFMAQ(ASET, mi, BSET, ni)                                                \
    __builtin_amdgcn_s_setprio(1);                                               \
    _Pragma("unroll")                                                            \
    for (int im = 0; im < 4; ++im)                                               \
        _Pragma("unroll")                                                        \
        for (int jn = 0; jn < 2; ++jn)                                           \
            _Pragma("unroll")                                                    \
            for (int kk = 0; kk < 2; ++kk)                                       \
                acc[(mi) + im][(ni) + jn] = __builtin_amdgcn_mfma_f32_16x16x32_bf16( \
                    ASET[im][kk], BSET[jn][kk], acc[(mi) + im][(ni) + jn], 0, 0, 0); \
    __builtin_amdgcn_s_setprio(0);

    // Per-tile schedule (4 barriers). All reads issue 2 phases before consumption.
    //  p0: stage A1(E+1); BAR; MFMA q0xB0; read A1h <- Aq1(E)          [gate: E-1 p3]
    //  p1: stage A0(E+2); BAR; MFMA q0xB1; gate vmcnt(G1)              [proves A0/B0/B1(E+1)]
    //  p2: stage B0(E+2); BAR; MFMA q1xB0; read A0h,B0h <- (E+1)       [gate: p1]
    //  p3: stage B1(E+2); BAR; MFMA q1xB1; read B1h <- (E+1); vmcnt(G3)[proves A1(E+1)]
#define TILE_BODY(bcur, bnxt, EE, ST0, STN, RD, G1T, G1F, G3T, G3F)              \
    /* p0 */                                                                     \
    if (ST0) stageA((bnxt), 1, (EE) + 1);                                        \
    BARSCHED();                                                                  \
    MFMAQ(A0h, 0, B0h, 0);                                                       \
    READ_A8(A1h, (bcur) + 16384);                                                \
    __builtin_amdgcn_sched_barrier(0);                                           \
    /* p1 */                                                                     \
    if (STN) stageA((bcur), 0, (EE) + 2);                                        \
    BARSCHED();                                                                  \
    MFMAQ(A0h, 0, B1h, 2);                                                       \
    if (RD) { if (STN) VMCNT(G1T); else VMCNT(G1F); }                            \
    __builtin_amdgcn_sched_barrier(0);                                           \
    /* p2 */                                                                     \
    if (STN) stageB((bcur), 0, (EE) + 2);                                        \
    BARSCHED();                                                                  \
    MFMAQ(A1h, 4, B0h, 0);                                                       \
    if (RD) { READ_A8(A0h, (bnxt)); READ_B4(B0h, (bnxt) + 32768); }              \
    __builtin_amdgcn_sched_barrier(0);                                           \
    /* p3 */                                                                     \
    if (STN) stageB((bcur), 1, (EE) + 2);                                        \
    BARSCHED();                                                                  \
    MFMAQ(A1h, 4, B1h, 2);                                                       \
    if (RD) { READ_B4(B1h, (bnxt) + 32768 + 16384);                              \
              if (STN) VMCNT(G3T); else VMCNT(G3F); }                            \
    __builtin_amdgcn_sched_barrier(0);

    // ---- prologue ----
    // issue order matters for gate arithmetic:
    // [A0(0),B0(0),B1(0),A1(0),A0(1),B0(1),B1(1)] = 14 loads
    stageA(b0, 0, 0); stageB(b0, 0, 0); stageB(b0, 1, 0); stageA(b0, 1, 0);
    stageA(b1, 0, 1); stageB(b1, 0, 1); stageB(b1, 1, 1);
    VMCNT(8);                        // A0/B0/B1(0) resident
    __builtin_amdgcn_s_barrier();
    __builtin_amdgcn_sched_barrier(0);
    READ_A8(A0h, b0);                // Aq0(0)
    READ_B4(B0h, b0 + 32768);        // B0(0)
    READ_B4(B1h, b0 + 32768 + 16384);// B1(0)
    VMCNT(6);                        // A1(0) resident (gate for tile0 p0 read)
    __builtin_amdgcn_sched_barrier(0);

    for (int kt2 = 0; kt2 < NT / 2; ++kt2) {
        const int  E  = kt2 * 2;
        const bool st = (kt2 < NT / 2 - 1);
        // tile E (b0): ST0 always (E+1<=63); tail gates G1=2, G3=0 on tile 62
        TILE_BODY(b0, b1, E, true, st, true, 4, 2, 6, 0);
        // tile E+1 (b1): everything guarded by st; steady gates 4/6
        TILE_BODY(b1, b0, E + 1, st, st, st, 4, 4, 6, 6);
    }

    // ---- epilogue: y = acc*scale + bias ----
    const float s = scale[0];
    #pragma unroll
    for (int fm = 0; fm < 8; ++fm) {
        const size_t row0 = rowM0 + wm * 128 + fm * 16 + (l >> 4) * 4;
        #pragma unroll
        for (int fn = 0; fn < 4; ++fn) {
            const int col = (int)rowN0 + wn * 64 + fn * 16 + (l & 15);
            const float bv = bias[col];
            float* o = out + row0 * N_DIM + col;
            #pragma unroll
            for (int r = 0; r < 4; ++r)
                o[(size_t)r * N_DIM] = acc[fm][fn][r] * s + bv;
        }
    }
}

// ---------- launch ----------
extern "C" void kernel_launch(void* const* d_in, const int* in_sizes, int n_in,
                              void* d_out, int out_size, void* d_ws, size_t ws_size,
                              hipStream_t stream) {
    const float* x     = (const float*)d_in[0];
    const int*   w     = (const int*)d_in[1];
    const float* scale = (const float*)d_in[2];
    const float* bias  = (const float*)d_in[3];
    float*       out   = (float*)d_out;

    const size_t x_elems  = (size_t)M_DIM * K_DIM;
    const size_t w_elems  = (size_t)N_DIM * K_DIM;
    const size_t xb_bytes = x_elems * 2;
    const size_t wb_bytes = w_elems * 2;
    if (ws_size < xb_bytes + wb_bytes) return;

    unsigned short* xbp = (unsigned short*)d_ws;
    unsigned short* wbp = (unsigned short*)((char*)d_ws + xb_bytes);

    {
        int n8 = (int)(x_elems / 8);
        cvt_x_kernel<<<(n8 + 255) / 256, 256, 0, stream>>>(x, (u16x8*)xbp, n8);
    }
    {
        int n8 = (int)(w_elems / 8);
        cvt_w_kernel<<<(n8 + 255) / 256, 256, 0, stream>>>(w, (u16x8*)wbp, n8);
    }
    gemm2_kernel<<<MT2 * NT2, 512, 0, stream>>>(xbp, wbp, scale, bias, out);
}

// Round 7
// 745.464 us; speedup vs baseline: 2.0056x; 2.0056x over previous
//
#include <hip/hip_runtime.h>
#include <stdint.h>

// ---------- types ----------
typedef __attribute__((ext_vector_type(8)))  short          short8;   // 8 x bf16
typedef __attribute__((ext_vector_type(8)))  unsigned short u16x8;
typedef __attribute__((ext_vector_type(16))) float          f32x16;

#define K_DIM 4096
#define N_DIM 11008
#define M_DIM 8192
#define BM 256
#define BN 256
#define BK 64
#define NT (K_DIM / BK)     // 64 K-tiles
#define MT2 (M_DIM / BM)    // 32
#define NT2 (N_DIM / BN)    // 43

// RNE float -> bf16 bits
__device__ __forceinline__ unsigned short f2bf(float f) {
    union { float f; uint32_t u; } v; v.f = f;
    uint32_t u = v.u;
    return (unsigned short)((u + 0x7FFFu + ((u >> 16) & 1u)) >> 16);
}

// ---------- conversion kernels (8 elems/thread) ----------
__global__ void cvt_x_kernel(const float* __restrict__ x,
                             u16x8* __restrict__ xb, int n8) {
    int i = blockIdx.x * blockDim.x + threadIdx.x;
    if (i >= n8) return;
    const float4* p = (const float4*)x + 2 * (size_t)i;
    float4 a = p[0], b = p[1];
    u16x8 o;
    o[0] = f2bf(a.x); o[1] = f2bf(a.y); o[2] = f2bf(a.z); o[3] = f2bf(a.w);
    o[4] = f2bf(b.x); o[5] = f2bf(b.y); o[6] = f2bf(b.z); o[7] = f2bf(b.w);
    xb[i] = o;
}

__global__ void cvt_w_kernel(const int* __restrict__ w,
                             u16x8* __restrict__ wb, int n8) {
    int i = blockIdx.x * blockDim.x + threadIdx.x;
    if (i >= n8) return;
    const int4* p = (const int4*)w + 2 * (size_t)i;
    int4 a = p[0], b = p[1];
    u16x8 o;
    o[0] = f2bf((float)a.x); o[1] = f2bf((float)a.y);
    o[2] = f2bf((float)a.z); o[3] = f2bf((float)a.w);
    o[4] = f2bf((float)b.x); o[5] = f2bf((float)b.y);
    o[6] = f2bf((float)b.z); o[7] = f2bf((float)b.w);
    wb[i] = o;
}

// ---------- 256x256 GEMM, R5 schedule, 32x32x16 MFMA ----------
#define GLDS16(gsrc, ldst)                                                       \
    __builtin_amdgcn_global_load_lds(                                            \
        (const __attribute__((address_space(1))) void*)(gsrc),                   \
        (__attribute__((address_space(3))) void*)(ldst), 16, 0, 0)

#define BARSCHED() do { __builtin_amdgcn_s_barrier();                            \
                        __builtin_amdgcn_sched_barrier(0); } while (0)
#define VMCNT(n)  asm volatile("s_waitcnt vmcnt(" #n ")" ::: "memory")

__global__ __launch_bounds__(512, 2) void gemm2_kernel(
    const unsigned short* __restrict__ xb,   // [8192][4096] bf16
    const unsigned short* __restrict__ wb,   // [11008][4096] bf16
    const float* __restrict__ scale,
    const float* __restrict__ bias,
    float* __restrict__ out)
{
    __shared__ unsigned char sm[131072];
    char* smc = (char*)sm;

    const int T  = threadIdx.x;
    const int l  = T & 63;
    const int wv = T >> 6;
    const int wm = wv >> 2;      // 0..1
    const int wn = wv & 3;       // 0..3

    // XCD-aware, bn-major grid map (B panel shared across XCDs via L3)
    const int orig = blockIdx.x;
    const int xcd  = orig & 7;
    const int p    = orig >> 3;          // 0..171
    const int bm   = xcd * 4 + (p & 3);  // 0..31
    const int bn   = p >> 2;             // 0..42
    const size_t rowM0 = (size_t)bm * BM;
    const size_t rowN0 = (size_t)bn * BN;

    // ---- staging precompute (pre-swizzled global source, linear LDS dest) ----
    const int rowT = T >> 3;                                        // 0..63
    const int colT = ((((T & 7) * 16) ^ ((rowT & 7) << 4)) >> 1);   // elems
    const unsigned short* pAg = xb + (rowM0 + rowT) * (size_t)K_DIM + colT;
    const unsigned short* pBg = wb + (rowN0 + ((rowT >> 5) << 6) + (rowT & 31)) * (size_t)K_DIM + colT;

    auto stageA = [&](char* base, int Q, int kt) {
        #pragma unroll
        for (int c = 0; c < 2; ++c) {
            const unsigned short* src = pAg + (size_t)(c * 128 + Q * 64) * K_DIM + (size_t)kt * BK;
            char* dst = base + Q * 16384 + c * 8192 + T * 16;
            GLDS16(src, dst);
        }
    };
    auto stageB = [&](char* base, int Q, int kt) {
        #pragma unroll
        for (int c = 0; c < 2; ++c) {
            const unsigned short* src = pBg + (size_t)(c * 128 + Q * 32) * K_DIM + (size_t)kt * BK;
            char* dst = base + 32768 + Q * 16384 + c * 8192 + T * 16;
            GLDS16(src, dst);
        }
    };

    // ---- ds_read precompute (32x32x16 fragments) ----
    // A frag (m-half h, m-frag f, k-frag ks): lane l -> row = h*64+f*32+(l&31)
    //   within wave's wm region; byte = (wm*64 + f*32 + (l&31))*128 + lowkk[ks], +h*16384
    // B frag (n-frag j): rho = (wn>>1)*64 + (wn&1)*32 + (l&31), region +j*16384
    const int sw = (l & 7) << 4;
    int lowkk[4];
    #pragma unroll
    for (int ks = 0; ks < 4; ++ks)
        lowkk[ks] = ((((ks << 1) | (l >> 5)) << 4)) ^ sw;
    const int arow = wm * 64 + (l & 31);
    const int brow = (wn >> 1) * 64 + (wn & 1) * 32 + (l & 31);

    f32x16 acc32[4][2];
    #pragma unroll
    for (int i = 0; i < 4; ++i)
        #pragma unroll
        for (int j = 0; j < 2; ++j)
            #pragma unroll
            for (int r = 0; r < 16; ++r)
                acc32[i][j][r] = 0.f;

    short8 Ah[2][4];    // [m-frag f][k-frag ks] of current m-half
    short8 B0h[4];      // n-frag 0, all ks
    short8 B1h[4];      // n-frag 1, all ks

    char* const b0 = smc;
    char* const b1 = smc + 65536;

#define READ_A32(base)                                                           \
    _Pragma("unroll")                                                            \
    for (int f = 0; f < 2; ++f)                                                  \
        _Pragma("unroll")                                                        \
        for (int ks = 0; ks < 4; ++ks)                                           \
            Ah[f][ks] = *(const short8*)((base) + (arow + f * 32) * 128 + lowkk[ks]);
#define READ_B32(dst, base)                                                      \
    _Pragma("unroll")                                                            \
    for (int ks = 0; ks < 4; ++ks)                                               \
        dst[ks] = *(const short8*)((base) + brow * 128 + lowkk[ks]);
#define MFMAQ32(h, BSET, j)                                                      \
    __builtin_amdgcn_s_setprio(1);                                               \
    _Pragma("unroll")                                                            \
    for (int ks = 0; ks < 4; ++ks)                                               \
        _Pragma("unroll")                                                        \
        for (int f = 0; f < 2; ++f)                                              \
            acc32[(h) * 2 + f][j] = __builtin_amdgcn_mfma_f32_32x32x16_bf16(     \
                Ah[f][ks], BSET[ks], acc32[(h) * 2 + f][j], 0, 0, 0);            \
    __builtin_amdgcn_s_setprio(0);

    // R5 tile schedule, 5 barriers/tile, gates unchanged:
    //  p0: READ B1h(cur) [pre-BAR]; stage A1(E+1); BAR; MFMA h0 x B0h
    //  p1: stage A0(E+2); BAR; MFMA h0 x B1h; READ Ah <- h1(cur)
    //  p2: stage B0(E+2); BAR; MFMA h1 x B0h; gate vmcnt
    //  p3: stage B1(E+2); BAR; MFMA h1 x B1h; READ Ah<-h0(next), B0h(next);
    //      boundary vmcnt; BAR
#define TILE_BODY(bcur, bnxt, EE, ST0, STN, RD)                                  \
    READ_B32(B1h, (bcur) + 32768 + 16384);                                       \
    if (ST0) stageA((bnxt), 1, (EE) + 1);                                        \
    BARSCHED();                                                                  \
    MFMAQ32(0, B0h, 0);                                                          \
    __builtin_amdgcn_sched_barrier(0);                                           \
    if (STN) stageA((bcur), 0, (EE) + 2);                                        \
    BARSCHED();                                                                  \
    MFMAQ32(0, B1h, 1);                                                          \
    READ_A32((bcur) + 16384);                                                    \
    __builtin_amdgcn_sched_barrier(0);                                           \
    if (STN) stageB((bcur), 0, (EE) + 2);                                        \
    BARSCHED();                                                                  \
    MFMAQ32(1, B0h, 0);                                                          \
    if (STN) VMCNT(8); else VMCNT(4);                                            \
    __builtin_amdgcn_sched_barrier(0);                                           \
    if (STN) stageB((bcur), 1, (EE) + 2);                                        \
    BARSCHED();                                                                  \
    MFMAQ32(1, B1h, 1);                                                          \
    if (RD) { READ_A32(bnxt); READ_B32(B0h, (bnxt) + 32768); }                   \
    if (STN) VMCNT(6); else VMCNT(0);                                            \
    __builtin_amdgcn_s_barrier();                                                \
    __builtin_amdgcn_sched_barrier(0);

    // ---- prologue: [A0(0),B0(0),B1(0),A1(0),A0(1),B0(1),B1(1)] = 14 loads ----
    stageA(b0, 0, 0); stageB(b0, 0, 0); stageB(b0, 1, 0); stageA(b0, 1, 0);
    stageA(b1, 0, 1); stageB(b1, 0, 1); stageB(b1, 1, 1);
    VMCNT(8);                        // A0/B0/B1(0) resident
    __builtin_amdgcn_s_barrier();
    __builtin_amdgcn_sched_barrier(0);
    READ_A32(b0);                    // Ah = h0(0)
    READ_B32(B0h, b0 + 32768);       // B0(0)
    VMCNT(6);                        // A1(0) resident (for p1's read)
    __builtin_amdgcn_sched_barrier(0);

    for (int kt2 = 0; kt2 < NT / 2; ++kt2) {
        const int  E  = kt2 * 2;
        const bool st = (kt2 < NT / 2 - 1);
        TILE_BODY(b0, b1, E, true, st, true);
        TILE_BODY(b1, b0, E + 1, st, st, st);
    }

    // ---- epilogue: y = acc*scale + bias ----
    // C/D 32x32 map: col = l&31, row = (r&3) + 8*(r>>2) + 4*(l>>5)
    const float s = scale[0];
    #pragma unroll
    for (int mi = 0; mi < 4; ++mi) {
        const size_t rbase = rowM0 + wm * 128 + mi * 32 + (l >> 5) * 4;
        #pragma unroll
        for (int j = 0; j < 2; ++j) {
            const int col = (int)rowN0 + wn * 64 + j * 32 + (l & 31);
            const float bv = bias[col];
            float* o = out + rbase * N_DIM + col;
            #pragma unroll
            for (int r = 0; r < 16; ++r)
                o[(size_t)((r & 3) + 8 * (r >> 2)) * N_DIM] = acc32[mi][j][r] * s + bv;
        }
    }
}

// ---------- launch ----------
extern "C" void kernel_launch(void* const* d_in, const int* in_sizes, int n_in,
                              void* d_out, int out_size, void* d_ws, size_t ws_size,
                              hipStream_t stream) {
    const float* x     = (const float*)d_in[0];
    const int*   w     = (const int*)d_in[1];
    const float* scale = (const float*)d_in[2];
    const float* bias  = (const float*)d_in[3];
    float*       out   = (float*)d_out;

    const size_t x_elems  = (size_t)M_DIM * K_DIM;
    const size_t w_elems  = (size_t)N_DIM * K_DIM;
    const size_t xb_bytes = x_elems * 2;
    const size_t wb_bytes = w_elems * 2;
    if (ws_size < xb_bytes + wb_bytes) return;

    unsigned short* xbp = (unsigned short*)d_ws;
    unsigned short* wbp = (unsigned short*)((char*)d_ws + xb_bytes);

    {
        int n8 = (int)(x_elems / 8);
        cvt_x_kernel<<<(n8 + 255) / 256, 256, 0, stream>>>(x, (u16x8*)xbp, n8);
    }
    {
        int n8 = (int)(w_elems / 8);
        cvt_w_kernel<<<(n8 + 255) / 256, 256, 0, stream>>>(w, (u16x8*)wbp, n8);
    }
    gemm2_kernel<<<MT2 * NT2, 512, 0, stream>>>(xbp, wbp, scale, bias, out);
}

// Round 8
// 432.182 us; speedup vs baseline: 3.4594x; 1.7249x over previous
//
#include <hip/hip_runtime.h>
#include <stdint.h>

// ---------- types ----------
typedef __attribute__((ext_vector_type(4))) int   int4v;   // 4 dwords = 16 int8
typedef __attribute__((ext_vector_type(4))) float f32x4;

#define K_DIM 4096
#define N_DIM 11008
#define M_DIM 8192
#define BM 256
#define BN 256
#define BKB 128             // K-bytes (= K elems, int8) per tile
#define NT (K_DIM / BKB)    // 32 K-tiles
#define MT2 (M_DIM / BM)    // 32
#define NT2 (N_DIM / BN)    // 43

// ---------- x quantization: per-row int8, s_r = max|x_row|/127 ----------
__global__ __launch_bounds__(256) void quant_x_kernel(
    const float* __restrict__ x, unsigned char* __restrict__ xq,
    float* __restrict__ srow)
{
    const int row = blockIdx.x;                       // 0..8191
    const float4* xr = (const float4*)(x + (size_t)row * K_DIM);
    float4 v[4];
    float m = 0.f;
    #pragma unroll
    for (int i = 0; i < 4; ++i) {
        v[i] = xr[threadIdx.x + 256 * i];
        m = fmaxf(m, fmaxf(fmaxf(fabsf(v[i].x), fabsf(v[i].y)),
                           fmaxf(fabsf(v[i].z), fabsf(v[i].w))));
    }
    #pragma unroll
    for (int off = 32; off; off >>= 1) m = fmaxf(m, __shfl_xor(m, off, 64));
    __shared__ float wmax[4];
    if ((threadIdx.x & 63) == 0) wmax[threadIdx.x >> 6] = m;
    __syncthreads();
    const float mb  = fmaxf(fmaxf(wmax[0], wmax[1]), fmaxf(wmax[2], wmax[3]));
    const float s   = (mb > 0.f) ? mb * (1.f / 127.f) : 1.f;
    const float inv = (mb > 0.f) ? 127.f / mb : 0.f;
    if (threadIdx.x == 0) srow[row] = s;
    uint32_t* oq = (uint32_t*)(xq + (size_t)row * K_DIM);
    #pragma unroll
    for (int i = 0; i < 4; ++i) {
        int a = __float2int_rn(v[i].x * inv), b = __float2int_rn(v[i].y * inv);
        int c = __float2int_rn(v[i].z * inv), d = __float2int_rn(v[i].w * inv);
        oq[threadIdx.x + 256 * i] =
            (a & 0xff) | ((b & 0xff) << 8) | ((c & 0xff) << 16) | ((d & 0xff) << 24);
    }
}

// ---------- w: int32 -> int8 (exact), 8/thread ----------
__global__ void cvt_w8_kernel(const int* __restrict__ w,
                              uint2* __restrict__ wq, int n8) {
    int i = blockIdx.x * blockDim.x + threadIdx.x;
    if (i >= n8) return;
    const int4* p = (const int4*)w + 2 * (size_t)i;
    int4 a = p[0], b = p[1];
    uint32_t lo = (a.x & 0xff) | ((a.y & 0xff) << 8) | ((a.z & 0xff) << 16) | ((a.w & 0xff) << 24);
    uint32_t hi = (b.x & 0xff) | ((b.y & 0xff) << 8) | ((b.z & 0xff) << 16) | ((b.w & 0xff) << 24);
    wq[i] = (uint2){lo, hi};
}

// ---------- 256x256 int8 GEMM, R5 schedule (proven ledger), 16x16x64 i8 ----------
#define GLDS16(gsrc, ldst)                                                       \
    __builtin_amdgcn_global_load_lds(                                            \
        (const __attribute__((address_space(1))) void*)(gsrc),                   \
        (__attribute__((address_space(3))) void*)(ldst), 16, 0, 0)

#define BARSCHED() do { __builtin_amdgcn_s_barrier();                            \
                        __builtin_amdgcn_sched_barrier(0); } while (0)
#define VMCNT(n)  asm volatile("s_waitcnt vmcnt(" #n ")" ::: "memory")

__global__ __launch_bounds__(512, 2) void gemm2_kernel(
    const unsigned char* __restrict__ xq,   // [8192][4096] int8
    const unsigned char* __restrict__ wq,   // [11008][4096] int8
    const float* __restrict__ srow,         // [8192] per-row x scale
    const float* __restrict__ scale,        // [1]
    const float* __restrict__ bias,         // [11008]
    float* __restrict__ out)                // [8192][11008]
{
    __shared__ unsigned char sm[131072];
    char* smc = (char*)sm;

    const int T  = threadIdx.x;
    const int l  = T & 63;
    const int wv = T >> 6;
    const int wm = wv >> 2;      // 0..1
    const int wn = wv & 3;       // 0..3

    // XCD-aware, bn-major grid map (B panel shared across XCDs via L3)
    const int orig = blockIdx.x;
    const int xcd  = orig & 7;
    const int p    = orig >> 3;          // 0..171
    const int bm   = xcd * 4 + (p & 3);  // 0..31
    const int bn   = p >> 2;             // 0..42
    const size_t rowM0 = (size_t)bm * BM;
    const size_t rowN0 = (size_t)bn * BN;

    // ---- staging precompute (pre-swizzled global source, linear LDS dest) ----
    const int rowT = T >> 3;                                          // 0..63
    const int colT = (((T & 7) * 16) ^ ((rowT & 7) << 4));            // BYTES
    const unsigned char* pAg = xq + (rowM0 + rowT) * (size_t)K_DIM + colT;
    const unsigned char* pBg = wq + (rowN0 + ((rowT >> 5) << 6) + (rowT & 31)) * (size_t)K_DIM + colT;

    auto stageA = [&](char* base, int Q, int kt) {
        #pragma unroll
        for (int c = 0; c < 2; ++c) {
            const unsigned char* src = pAg + (size_t)(c * 128 + Q * 64) * K_DIM + (size_t)kt * BKB;
            char* dst = base + Q * 16384 + c * 8192 + T * 16;
            GLDS16(src, dst);
        }
    };
    auto stageB = [&](char* base, int Q, int kt) {
        #pragma unroll
        for (int c = 0; c < 2; ++c) {
            const unsigned char* src = pBg + (size_t)(c * 128 + Q * 32) * K_DIM + (size_t)kt * BKB;
            char* dst = base + 32768 + Q * 16384 + c * 8192 + T * 16;
            GLDS16(src, dst);
        }
    };

    // ---- ds_read precompute (16x16x64 i8 fragments; bytes identical to R5) ----
    const int sw     = (l & 7) << 4;
    const int inrow0 = (l >> 4) * 16;          // 16-byte k-slice per lane
    const int lowk0  = inrow0 ^ sw;            // kk=0 (k 0..63)
    const int lowk1  = (64 + inrow0) ^ sw;     // kk=1 (k 64..127)
    const int arow   = wm * 64 + (l & 15);
    const int brow   = wn * 32 + (l & 15);

    int4v acc[8][4];
    #pragma unroll
    for (int i = 0; i < 8; ++i)
        #pragma unroll
        for (int j = 0; j < 4; ++j)
            acc[i][j] = (int4v){0, 0, 0, 0};

    int4v Ah[4][2];   // current A quadrant
    int4v Bh[4][2];   // Bh[0..1]=B0(cur), Bh[2..3]=B1(cur)

    char* const b0 = smc;
    char* const b1 = smc + 65536;

#define READ_A(base)                                                             \
    _Pragma("unroll")                                                            \
    for (int im = 0; im < 4; ++im) {                                             \
        Ah[im][0] = *(const int4v*)((base) + (arow + im * 16) * 128 + lowk0);    \
        Ah[im][1] = *(const int4v*)((base) + (arow + im * 16) * 128 + lowk1);    \
    }
#define READ_B(base, f0)                                                         \
    _Pragma("unroll")                                                            \
    for (int f = 0; f < 2; ++f) {                                                \
        Bh[(f0) + f][0] = *(const int4v*)((base) + (brow + f * 16) * 128 + lowk0); \
        Bh[(f0) + f][1] = *(const int4v*)((base) + (brow + f * 16) * 128 + lowk1); \
    }
#define MFMAQ(mi, ni)                                                            \
    __builtin_amdgcn_s_setprio(1);                                               \
    _Pragma("unroll")                                                            \
    for (int im = 0; im < 4; ++im)                                               \
        _Pragma("unroll")                                                        \
        for (int jn = 0; jn < 2; ++jn)                                           \
            _Pragma("unroll")                                                    \
            for (int kk = 0; kk < 2; ++kk)                                       \
                acc[(mi) + im][(ni) + jn] = __builtin_amdgcn_mfma_i32_16x16x64_i8( \
                    Ah[im][kk], Bh[(ni) + jn][kk], acc[(mi) + im][(ni) + jn], 0, 0, 0); \
    __builtin_amdgcn_s_setprio(0);

#define TILE_BODY(bcur, bnxt, EE, ST0, STN, RD)                                  \
    READ_B((bcur) + 32768 + 16384, 2);                                           \
    if (ST0) stageA((bnxt), 1, (EE) + 1);                                        \
    BARSCHED();                                                                  \
    MFMAQ(0, 0);                                                                 \
    __builtin_amdgcn_sched_barrier(0);                                           \
    if (STN) stageA((bcur), 0, (EE) + 2);                                        \
    BARSCHED();                                                                  \
    MFMAQ(0, 2);                                                                 \
    READ_A((bcur) + 16384);                                                      \
    __builtin_amdgcn_sched_barrier(0);                                           \
    if (STN) stageB((bcur), 0, (EE) + 2);                                        \
    BARSCHED();                                                                  \
    MFMAQ(4, 0);                                                                 \
    if (STN) VMCNT(8); else VMCNT(4);                                            \
    __builtin_amdgcn_sched_barrier(0);                                           \
    if (STN) stageB((bcur), 1, (EE) + 2);                                        \
    BARSCHED();                                                                  \
    MFMAQ(4, 2);                                                                 \
    if (RD) { READ_A(bnxt); READ_B((bnxt) + 32768, 0); }                         \
    if (STN) VMCNT(6); else VMCNT(0);                                            \
    __builtin_amdgcn_s_barrier();                                                \
    __builtin_amdgcn_sched_barrier(0);

    // ---- prologue: [A0(0),B0(0),B1(0),A1(0),A0(1),B0(1),B1(1)] = 14 loads ----
    stageA(b0, 0, 0); stageB(b0, 0, 0); stageB(b0, 1, 0); stageA(b0, 1, 0);
    stageA(b1, 0, 1); stageB(b1, 0, 1); stageB(b1, 1, 1);
    VMCNT(8);                        // A0/B0/B1(0) resident
    __builtin_amdgcn_s_barrier();
    __builtin_amdgcn_sched_barrier(0);
    READ_A(b0);                      // Aq0(0)
    READ_B(b0 + 32768, 0);           // B0(0)
    VMCNT(6);                        // A1(0) resident
    __builtin_amdgcn_sched_barrier(0);

    for (int kt2 = 0; kt2 < NT / 2; ++kt2) {
        const int  E  = kt2 * 2;
        const bool st = (kt2 < NT / 2 - 1);
        TILE_BODY(b0, b1, E, true, st, true);
        TILE_BODY(b1, b0, E + 1, st, st, st);
    }

    // ---- epilogue: y = acc * s_r * s_w + bias ----
    const float s = scale[0];
    #pragma unroll
    for (int fm = 0; fm < 8; ++fm) {
        const size_t row0 = rowM0 + wm * 128 + fm * 16 + (l >> 4) * 4;
        const float4 sr4 = *(const float4*)(srow + row0);
        #pragma unroll
        for (int fn = 0; fn < 4; ++fn) {
            const int col = (int)rowN0 + wn * 64 + fn * 16 + (l & 15);
            const float bv = bias[col];
            float* o = out + row0 * N_DIM + col;
            o[0]                  = (float)acc[fm][fn][0] * (sr4.x * s) + bv;
            o[(size_t)1 * N_DIM]  = (float)acc[fm][fn][1] * (sr4.y * s) + bv;
            o[(size_t)2 * N_DIM]  = (float)acc[fm][fn][2] * (sr4.z * s) + bv;
            o[(size_t)3 * N_DIM]  = (float)acc[fm][fn][3] * (sr4.w * s) + bv;
        }
    }
}

// ---------- launch ----------
extern "C" void kernel_launch(void* const* d_in, const int* in_sizes, int n_in,
                              void* d_out, int out_size, void* d_ws, size_t ws_size,
                              hipStream_t stream) {
    const float* x     = (const float*)d_in[0];
    const int*   w     = (const int*)d_in[1];
    const float* scale = (const float*)d_in[2];
    const float* bias  = (const float*)d_in[3];
    float*       out   = (float*)d_out;

    const size_t x_elems = (size_t)M_DIM * K_DIM;    // 33,554,432
    const size_t w_elems = (size_t)N_DIM * K_DIM;    // 45,088,768
    const size_t xq_off  = 0;
    const size_t wq_off  = x_elems;                  // bytes (int8)
    const size_t sr_off  = x_elems + w_elems;
    if (ws_size < sr_off + (size_t)M_DIM * 4) return;

    unsigned char* xqp = (unsigned char*)d_ws + xq_off;
    unsigned char* wqp = (unsigned char*)d_ws + wq_off;
    float*         srp = (float*)((unsigned char*)d_ws + sr_off);

    quant_x_kernel<<<M_DIM, 256, 0, stream>>>(x, xqp, srp);
    {
        int n8 = (int)(w_elems / 8);
        cvt_w8_kernel<<<(n8 + 255) / 256, 256, 0, stream>>>(w, (uint2*)wqp, n8);
    }
    gemm2_kernel<<<MT2 * NT2, 512, 0, stream>>>(xqp, wqp, srp, scale, bias, out);
}